// Round 6
// baseline (258.386 us; speedup 1.0000x reference)
//
#include <hip/hip_runtime.h>

typedef unsigned short u16;
typedef unsigned int u32;

typedef __bf16 bf16x8 __attribute__((ext_vector_type(8)));
typedef float floatx4 __attribute__((ext_vector_type(4)));

__device__ __forceinline__ u16 f2bf(float f) {
    union { float f; u32 u; } c; c.f = f;
    u32 u = c.u;
    u32 r = u + 0x7FFFu + ((u >> 16) & 1u);   // round-to-nearest-even
    return (u16)(r >> 16);
}
__device__ __forceinline__ float bf2f(u16 x) {
    union { u32 u; float f; } c; c.u = ((u32)x) << 16; return c.f;
}

// Stage 8 consecutive f32 as bf16 hi/lo pairs into LDS (16B each).
__device__ __forceinline__ void stage8(const float* __restrict__ src,
                                       u16* dh, u16* dl) {
    float4 v0 = *(const float4*)src;
    float4 v1 = *(const float4*)(src + 4);
    float xs[8] = {v0.x, v0.y, v0.z, v0.w, v1.x, v1.y, v1.z, v1.w};
    u16 h[8], l[8];
#pragma unroll
    for (int e = 0; e < 8; e++) {
        u16 hh = f2bf(xs[e]);
        h[e] = hh;
        l[e] = f2bf(xs[e] - bf2f(hh));   // exact residual, then RNE
    }
    *(uint4*)dh = *(uint4*)h;
    *(uint4*)dl = *(uint4*)l;
}

// ---------------------------------------------------------------------------
// Split-precision GEMM: sim = img * txt^T, f32 in, f32 out, ~16-bit mantissa.
// C = Ah*Bh + Ah*Bl + Al*Bh  (bf16 MFMA x3 per fragment pair).
// 128x128 tile / 256 threads, 2x2 waves of 64x64, 16x16x32 bf16 MFMA.
// ---------------------------------------------------------------------------
__global__ __launch_bounds__(256) void gemm_split(const float* __restrict__ A,
                                                  const float* __restrict__ B,
                                                  float* __restrict__ C) {
    __shared__ __align__(16) u16 lAh[128 * 40];
    __shared__ __align__(16) u16 lAl[128 * 40];
    __shared__ __align__(16) u16 lBh[128 * 40];
    __shared__ __align__(16) u16 lBl[128 * 40];
    const int tid  = threadIdx.x;
    const int wave = tid >> 6, lane = tid & 63;
    const int lr = lane & 15, quad = lane >> 4;
    const int waveM = wave >> 1, waveN = wave & 1;
    const int rowBase = blockIdx.y * 128;
    const int colBase = blockIdx.x * 128;

    const int c0r = tid >> 2, c1r = c0r + 64;
    const int ck  = (tid & 3) * 8;

    floatx4 acc[4][4];
#pragma unroll
    for (int mi = 0; mi < 4; mi++)
#pragma unroll
        for (int ni = 0; ni < 4; ni++) acc[mi][ni] = (floatx4)0.0f;

    for (int k0 = 0; k0 < 512; k0 += 32) {
        __syncthreads();
        stage8(&A[(size_t)(rowBase + c0r) * 512 + k0 + ck], &lAh[c0r * 40 + ck], &lAl[c0r * 40 + ck]);
        stage8(&A[(size_t)(rowBase + c1r) * 512 + k0 + ck], &lAh[c1r * 40 + ck], &lAl[c1r * 40 + ck]);
        stage8(&B[(size_t)(colBase + c0r) * 512 + k0 + ck], &lBh[c0r * 40 + ck], &lBl[c0r * 40 + ck]);
        stage8(&B[(size_t)(colBase + c1r) * 512 + k0 + ck], &lBh[c1r * 40 + ck], &lBl[c1r * 40 + ck]);
        __syncthreads();

        bf16x8 afh[4], afl[4], bfh[4], bfl[4];
#pragma unroll
        for (int mi = 0; mi < 4; mi++) {
            int off = (waveM * 64 + mi * 16 + lr) * 40 + quad * 8;
            afh[mi] = *(const bf16x8*)&lAh[off];
            afl[mi] = *(const bf16x8*)&lAl[off];
        }
#pragma unroll
        for (int ni = 0; ni < 4; ni++) {
            int off = (waveN * 64 + ni * 16 + lr) * 40 + quad * 8;
            bfh[ni] = *(const bf16x8*)&lBh[off];
            bfl[ni] = *(const bf16x8*)&lBl[off];
        }
#pragma unroll
        for (int mi = 0; mi < 4; mi++)
#pragma unroll
            for (int ni = 0; ni < 4; ni++) {
                acc[mi][ni] = __builtin_amdgcn_mfma_f32_16x16x32_bf16(afh[mi], bfh[ni], acc[mi][ni], 0, 0, 0);
                acc[mi][ni] = __builtin_amdgcn_mfma_f32_16x16x32_bf16(afh[mi], bfl[ni], acc[mi][ni], 0, 0, 0);
                acc[mi][ni] = __builtin_amdgcn_mfma_f32_16x16x32_bf16(afl[mi], bfh[ni], acc[mi][ni], 0, 0, 0);
            }
    }

    // C/D layout: col = lane&15, row = (lane>>4)*4 + reg   [m89/m91 verified]
#pragma unroll
    for (int mi = 0; mi < 4; mi++)
#pragma unroll
        for (int ni = 0; ni < 4; ni++) {
            int r0 = rowBase + waveM * 64 + mi * 16 + quad * 4;
            int c  = colBase + waveN * 64 + ni * 16 + lr;
#pragma unroll
            for (int r = 0; r < 4; r++)
                C[(size_t)(r0 + r) * 4096 + c] = acc[mi][ni][r];
        }
}

// ---------------------------------------------------------------------------
// In-place transpose, 64x64 f32 tiles, tile-pair swap.
// ---------------------------------------------------------------------------
__global__ __launch_bounds__(256) void transpose_inplace(float* __restrict__ M) {
    int tr = blockIdx.y, tc = blockIdx.x;
    if (tr > tc) return;
    __shared__ float tA[64 * 65];
    __shared__ float tB[64 * 65];
    int tid = threadIdx.x;
    int tx = tid & 63, ty = tid >> 6;
#pragma unroll
    for (int i = 0; i < 16; i++) {
        int r = i * 4 + ty;
        tA[r * 65 + tx] = M[(size_t)(tr * 64 + r) * 4096 + tc * 64 + tx];
    }
    if (tr != tc) {
#pragma unroll
        for (int i = 0; i < 16; i++) {
            int r = i * 4 + ty;
            tB[r * 65 + tx] = M[(size_t)(tc * 64 + r) * 4096 + tr * 64 + tx];
        }
    }
    __syncthreads();
#pragma unroll
    for (int i = 0; i < 16; i++) {
        int r = i * 4 + ty;
        M[(size_t)(tc * 64 + r) * 4096 + tr * 64 + tx] = tA[tx * 65 + r];
    }
    if (tr != tc) {
#pragma unroll
        for (int i = 0; i < 16; i++) {
            int r = i * 4 + ty;
            M[(size_t)(tr * 64 + r) * 4096 + tc * 64 + tx] = tB[tx * 65 + r];
        }
    }
}

// ---------------------------------------------------------------------------
// Per-row statistics + state update (all f32). One 256-thread block per row.
// Output sections (f32 elems after the 5 scalars):
//   s@(0+side)n, b@(2+side)n, u@(4+side)n, tau@(6+side)n.
// rowbuf: [(2*side+0)*4096 + i] = loss_row, [(2*side+1)*4096 + i] = tw_row.
// ---------------------------------------------------------------------------
__global__ __launch_bounds__(256) void row_process(
    const float* __restrict__ mat,
    const float* __restrict__ tau_in, const float* __restrict__ s_in,
    const float* __restrict__ b_in, const float* __restrict__ u_in,
    const int* __restrict__ ids, const int* __restrict__ epoch_p,
    float* __restrict__ out, float* __restrict__ rowbuf,
    long long n, int side) {
    const int i = blockIdx.x;
    const int tid = threadIdx.x;
    const int lane = tid & 63, wv = tid >> 6;
    const float* row = mat + (size_t)i * 4096;

    float4 v[4];
#pragma unroll
    for (int q = 0; q < 4; q++) v[q] = *(const float4*)&row[4 * (tid + 256 * q)];

    const int id = ids[i];
    const float tau   = tau_in[id];
    const float old_b = b_in[id];
    const float old_s = s_in[id];
    const float old_u = u_in[id];
    const float diag  = row[i];

    __shared__ float sred[8];

    // pass 1: row max (includes diagonal, as reference does)
    float m = -3.4e38f;
#pragma unroll
    for (int q = 0; q < 4; q++)
        m = fmaxf(m, fmaxf(fmaxf(v[q].x, v[q].y), fmaxf(v[q].z, v[q].w)));
    for (int o = 32; o > 0; o >>= 1) m = fmaxf(m, __shfl_xor(m, o));
    if (lane == 0) sred[wv] = m;
    __syncthreads();
    m = fmaxf(fmaxf(sred[0], sred[1]), fmaxf(sred[2], sred[3]));
    const float b_row = fmaxf((m - diag) / tau, old_b);
    __syncthreads();

    // pass 2: S0 = sum exp(idt-b), S1 = sum idt*exp(idt-b), over j != i
    float S0 = 0.f, S1 = 0.f;
#pragma unroll
    for (int q = 0; q < 4; q++) {
        int jb = 4 * (tid + 256 * q);
        float vals[4] = {v[q].x, v[q].y, v[q].z, v[q].w};
#pragma unroll
        for (int e = 0; e < 4; e++) {
            int j = jb + e;
            if (j != i) {
                float idt = (vals[e] - diag) / tau;
                float ex = expf(idt - b_row);
                S0 += ex;
                S1 += idt * ex;
            }
        }
    }
    for (int o = 32; o > 0; o >>= 1) { S0 += __shfl_xor(S0, o); S1 += __shfl_xor(S1, o); }
    if (lane == 0) { sred[wv] = S0; sred[4 + wv] = S1; }
    __syncthreads();

    if (tid == 0) {
        S0 = sred[0] + sred[1] + sred[2] + sred[3];
        S1 = sred[4] + sred[5] + sred[6] + sred[7];
        float g = S0;
        float sI = (*epoch_p == 0) ? g
                 : 0.2f * old_s * expf(old_b - b_row) + 0.8f * g;
        float denom = sI + 1e-10f;
        float wsum = S1 / denom;
        float lossr = tau * wsum;
        float tw = logf(sI * (1.0f / 4095.0f)) + b_row + 8.0f - wsum;
        tw = fminf(fmaxf(tw, -5.0f), 5.0f);
        float uval = 0.5f * old_u + 0.5f * tw;
        float taun = fminf(fmaxf(tau - 1e-5f * uval, 0.005f), 0.05f);

        float* sect = out + 5;
        sect[(size_t)(0 + side) * (size_t)n + id] = sI;
        sect[(size_t)(2 + side) * (size_t)n + id] = b_row;
        sect[(size_t)(4 + side) * (size_t)n + id] = uval;
        sect[(size_t)(6 + side) * (size_t)n + id] = taun;

        rowbuf[(2 * side + 0) * 4096 + i] = lossr;
        rowbuf[(2 * side + 1) * 4096 + i] = tw;
    }
}

// ---------------------------------------------------------------------------
// Bulk copy of the 8 f32 state arrays into their f32 output sections.
// ---------------------------------------------------------------------------
__global__ __launch_bounds__(256) void copy_all(
    const float* __restrict__ p0, const float* __restrict__ p1,
    const float* __restrict__ p2, const float* __restrict__ p3,
    const float* __restrict__ p4, const float* __restrict__ p5,
    const float* __restrict__ p6, const float* __restrict__ p7,
    float* __restrict__ out, long long n) {
    const float* src;
    switch (blockIdx.y) {
        case 0: src = p0; break; case 1: src = p1; break;
        case 2: src = p2; break; case 3: src = p3; break;
        case 4: src = p4; break; case 5: src = p5; break;
        case 6: src = p6; break; default: src = p7; break;
    }
    float* dst = out + 5 + (size_t)blockIdx.y * (size_t)n;
    long long base = (long long)blockIdx.x * 2048 + threadIdx.x;
#pragma unroll
    for (int k = 0; k < 8; k++) {
        long long e = base + k * 256;
        if (e < n) dst[e] = src[e];
    }
}

// ---------------------------------------------------------------------------
// Final 5 scalars, all f32:
//   out[0]=total_loss, out[1]=tau_img.mean, out[2]=tau_txt.mean,
//   out[3]=tw_i.mean,  out[4]=tw_t.mean.
// tau means gathered directly from inputs; loss/tw sums from rowbuf.
// ---------------------------------------------------------------------------
__global__ __launch_bounds__(256) void scalars(
    const float* __restrict__ rows,
    const float* __restrict__ tau_I, const float* __restrict__ tau_T,
    const int* __restrict__ image_ids, const int* __restrict__ text_ids,
    float* __restrict__ out) {
    int tid = threadIdx.x;
    int lane = tid & 63, wv = tid >> 6;
    float a[6] = {0, 0, 0, 0, 0, 0};
    for (int e = tid; e < 4096; e += 256) {
        a[0] += rows[0 * 4096 + e];       // loss_i
        a[1] += rows[1 * 4096 + e];       // tw_i
        a[2] += rows[2 * 4096 + e];       // loss_t
        a[3] += rows[3 * 4096 + e];       // tw_t
        a[4] += tau_I[image_ids[e]];      // old tau_img
        a[5] += tau_T[text_ids[e]];       // old tau_txt
    }
    __shared__ float sred[4][6];
#pragma unroll
    for (int k = 0; k < 6; k++)
        for (int o = 32; o > 0; o >>= 1) a[k] += __shfl_xor(a[k], o);
    if (lane == 0)
#pragma unroll
        for (int k = 0; k < 6; k++) sred[wv][k] = a[k];
    __syncthreads();
    if (tid == 0) {
#pragma unroll
        for (int k = 0; k < 6; k++)
            a[k] = sred[0][k] + sred[1][k] + sred[2][k] + sred[3][k];
        const float inv = 1.0f / 4096.0f;
        out[0] = (a[0] + a[2]) * inv;   // total_loss
        out[1] = a[4] * inv;            // tau_img.mean
        out[2] = a[5] * inv;            // tau_txt.mean
        out[3] = a[1] * inv;            // tw_i.mean
        out[4] = a[3] * inv;            // tw_t.mean
    }
}

extern "C" void kernel_launch(void* const* d_in, const int* in_sizes, int n_in,
                              void* d_out, int out_size, void* d_ws, size_t ws_size,
                              hipStream_t stream) {
    const float* img   = (const float*)d_in[0];
    const float* txt   = (const float*)d_in[1];
    const float* s_I   = (const float*)d_in[2];
    const float* s_T   = (const float*)d_in[3];
    const float* b_I   = (const float*)d_in[4];
    const float* b_T   = (const float*)d_in[5];
    const float* u_I   = (const float*)d_in[6];
    const float* u_T   = (const float*)d_in[7];
    const float* tau_I = (const float*)d_in[8];
    const float* tau_T = (const float*)d_in[9];
    const int* image_ids = (const int*)d_in[10];
    const int* text_ids  = (const int*)d_in[11];
    const int* epoch     = (const int*)d_in[12];
    float* out = (float*)d_out;        // f32 outputs (proven round 5)
    const long long n = in_sizes[2];   // 1,000,000 state entries per array

    // ws layout (within proven 72 MB):
    //   [0, 64MB):        sim f32 4096x4096
    //   [64MB, 64MB+64KB): rowbuf (4 x 4096 f32: loss_i, tw_i, loss_t, tw_t)
    float* sim  = (float*)d_ws;
    float* rows = (float*)((char*)d_ws + (size_t)64 * 1024 * 1024);

    gemm_split<<<dim3(32, 32), 256, 0, stream>>>(img, txt, sim);

    copy_all<<<dim3((int)((n + 2047) / 2048), 8), 256, 0, stream>>>(
        s_I, s_T, b_I, b_T, u_I, u_T, tau_I, tau_T, out, n);

    // image side (side=0): rows of sim
    row_process<<<4096, 256, 0, stream>>>(
        sim, tau_I, s_I, b_I, u_I, image_ids, epoch, out, rows, n, 0);

    transpose_inplace<<<dim3(64, 64), 256, 0, stream>>>(sim);

    // text side (side=1): rows of sim^T (= columns of sim)
    row_process<<<4096, 256, 0, stream>>>(
        sim, tau_T, s_T, b_T, u_T, text_ids, epoch, out, rows, n, 1);

    scalars<<<1, 256, 0, stream>>>(rows, tau_I, tau_T, image_ids, text_ids, out);
}

// Round 7
// 237.971 us; speedup vs baseline: 1.0858x; 1.0858x over previous
//
#include <hip/hip_runtime.h>

typedef unsigned short u16;
typedef unsigned int u32;

typedef __bf16 bf16x8 __attribute__((ext_vector_type(8)));
typedef float floatx4 __attribute__((ext_vector_type(4)));

__device__ __forceinline__ u16 f2bf(float f) {
    union { float f; u32 u; } c; c.f = f;
    u32 u = c.u;
    u32 r = u + 0x7FFFu + ((u >> 16) & 1u);   // round-to-nearest-even
    return (u16)(r >> 16);
}
__device__ __forceinline__ float bf2f(u16 x) {
    union { u32 u; float f; } c; c.u = ((u32)x) << 16; return c.f;
}

// async global->LDS DMA, 16B per lane; lds base must be wave-uniform
__device__ __forceinline__ void dma16(const u16* g, u16* l) {
#if __has_builtin(__builtin_amdgcn_global_load_lds)
    __builtin_amdgcn_global_load_lds(
        (const __attribute__((address_space(1))) u32*)g,
        (__attribute__((address_space(3))) u32*)l, 16, 0, 0);
#else
    // fallback: manual copy (lane-scattered), semantically equivalent
    int lane = threadIdx.x & 63;
    *(uint4*)(l + lane * 8) = *(const uint4*)(g);
#endif
}

// ---------------------------------------------------------------------------
// One-shot split: f32 features -> bf16 hi/lo arrays (linear layout).
// ---------------------------------------------------------------------------
__global__ __launch_bounds__(256) void presplit(
    const float* __restrict__ a, const float* __restrict__ b,
    u16* __restrict__ Ah, u16* __restrict__ Al,
    u16* __restrict__ Bh, u16* __restrict__ Bl, int n) {
    const float* src = blockIdx.y ? b : a;
    u16* dh = blockIdx.y ? Bh : Ah;
    u16* dl = blockIdx.y ? Bl : Al;
    int i = (blockIdx.x * 256 + threadIdx.x) * 8;
    if (i >= n) return;
    float4 v0 = *(const float4*)&src[i];
    float4 v1 = *(const float4*)&src[i + 4];
    float xs[8] = {v0.x, v0.y, v0.z, v0.w, v1.x, v1.y, v1.z, v1.w};
    u16 h[8], l[8];
#pragma unroll
    for (int e = 0; e < 8; e++) {
        h[e] = f2bf(xs[e]);
        l[e] = f2bf(xs[e] - bf2f(h[e]));
    }
    *(uint4*)&dh[i] = *(uint4*)h;
    *(uint4*)&dl[i] = *(uint4*)l;
}

// ---------------------------------------------------------------------------
// FAST GEMM: sim = A*B^T from pre-split bf16 hi/lo, DMA staging, unpadded LDS.
// Epilogue writes BOTH sim and simT (float4 stores for simT).
// C = Ah*Bh + Ah*Bl + Al*Bh, 128x128 tile, 16x16x32 MFMA, 2x2 waves.
// ---------------------------------------------------------------------------
__global__ __launch_bounds__(256) void gemm_dma(
    const u16* __restrict__ Ah, const u16* __restrict__ Al,
    const u16* __restrict__ Bh, const u16* __restrict__ Bl,
    float* __restrict__ sim, float* __restrict__ simT) {
    __shared__ __align__(16) u16 sAh[128 * 32];
    __shared__ __align__(16) u16 sAl[128 * 32];
    __shared__ __align__(16) u16 sBh[128 * 32];
    __shared__ __align__(16) u16 sBl[128 * 32];
    const int tid  = threadIdx.x;
    const int wave = tid >> 6, lane = tid & 63;
    const int lr = lane & 15, quad = lane >> 4;
    const int waveM = wave >> 1, waveN = wave & 1;
    const int rowBase = blockIdx.y * 128;
    const int colBase = blockIdx.x * 128;

    // DMA source coords for the two 4KB chunks this wave stages per tile:
    // chunk j: LDS byte base = wave*1024 + j*4096 (wave-uniform), lane adds 16B.
    const int o0 = wave * 1024 + lane * 16;
    const int o1 = o0 + 4096;
    const int r0s = o0 >> 6, c0s = (o0 & 63) >> 1;   // row, u16-col within k-block
    const int r1s = o1 >> 6, c1s = (o1 & 63) >> 1;
    const int l0 = wave * 512;          // u16 index of chunk-0 LDS base
    const int l1 = wave * 512 + 2048;   // u16 index of chunk-1 LDS base

    floatx4 acc[4][4];
#pragma unroll
    for (int mi = 0; mi < 4; mi++)
#pragma unroll
        for (int ni = 0; ni < 4; ni++) acc[mi][ni] = (floatx4)0.0f;

    for (int k0 = 0; k0 < 512; k0 += 32) {
        __syncthreads();
        dma16(&Ah[(size_t)(rowBase + r0s) * 512 + k0 + c0s], sAh + l0);
        dma16(&Ah[(size_t)(rowBase + r1s) * 512 + k0 + c1s], sAh + l1);
        dma16(&Al[(size_t)(rowBase + r0s) * 512 + k0 + c0s], sAl + l0);
        dma16(&Al[(size_t)(rowBase + r1s) * 512 + k0 + c1s], sAl + l1);
        dma16(&Bh[(size_t)(colBase + r0s) * 512 + k0 + c0s], sBh + l0);
        dma16(&Bh[(size_t)(colBase + r1s) * 512 + k0 + c1s], sBh + l1);
        dma16(&Bl[(size_t)(colBase + r0s) * 512 + k0 + c0s], sBl + l0);
        dma16(&Bl[(size_t)(colBase + r1s) * 512 + k0 + c1s], sBl + l1);
        __syncthreads();   // compiler emits vmcnt(0) drain before s_barrier

        bf16x8 afh[4], afl[4], bfh[4], bfl[4];
#pragma unroll
        for (int mi = 0; mi < 4; mi++) {
            int off = (waveM * 64 + mi * 16 + lr) * 32 + quad * 8;
            afh[mi] = *(const bf16x8*)&sAh[off];
            afl[mi] = *(const bf16x8*)&sAl[off];
        }
#pragma unroll
        for (int ni = 0; ni < 4; ni++) {
            int off = (waveN * 64 + ni * 16 + lr) * 32 + quad * 8;
            bfh[ni] = *(const bf16x8*)&sBh[off];
            bfl[ni] = *(const bf16x8*)&sBl[off];
        }
#pragma unroll
        for (int mi = 0; mi < 4; mi++)
#pragma unroll
            for (int ni = 0; ni < 4; ni++) {
                acc[mi][ni] = __builtin_amdgcn_mfma_f32_16x16x32_bf16(afh[mi], bfh[ni], acc[mi][ni], 0, 0, 0);
                acc[mi][ni] = __builtin_amdgcn_mfma_f32_16x16x32_bf16(afh[mi], bfl[ni], acc[mi][ni], 0, 0, 0);
                acc[mi][ni] = __builtin_amdgcn_mfma_f32_16x16x32_bf16(afl[mi], bfh[ni], acc[mi][ni], 0, 0, 0);
            }
    }

    // C/D layout: col = lane&15, row = (lane>>4)*4 + reg  [m89/m91 verified]
#pragma unroll
    for (int mi = 0; mi < 4; mi++)
#pragma unroll
        for (int ni = 0; ni < 4; ni++) {
            int rr = rowBase + waveM * 64 + mi * 16 + quad * 4;
            int cc = colBase + waveN * 64 + ni * 16 + lr;
#pragma unroll
            for (int r = 0; r < 4; r++)
                sim[(size_t)(rr + r) * 4096 + cc] = acc[mi][ni][r];
            float4 tv = {acc[mi][ni][0], acc[mi][ni][1], acc[mi][ni][2], acc[mi][ni][3]};
            *(float4*)&simT[(size_t)cc * 4096 + rr] = tv;   // rr % 4 == 0 -> 16B aligned
        }
}

// ---------------------------------------------------------------------------
// FALLBACK GEMM (round-6 proven): in-register split, padded LDS.
// ---------------------------------------------------------------------------
__device__ __forceinline__ void stage8(const float* __restrict__ src,
                                       u16* dh, u16* dl) {
    float4 v0 = *(const float4*)src;
    float4 v1 = *(const float4*)(src + 4);
    float xs[8] = {v0.x, v0.y, v0.z, v0.w, v1.x, v1.y, v1.z, v1.w};
    u16 h[8], l[8];
#pragma unroll
    for (int e = 0; e < 8; e++) {
        u16 hh = f2bf(xs[e]);
        h[e] = hh;
        l[e] = f2bf(xs[e] - bf2f(hh));
    }
    *(uint4*)dh = *(uint4*)h;
    *(uint4*)dl = *(uint4*)l;
}

__global__ __launch_bounds__(256) void gemm_split(const float* __restrict__ A,
                                                  const float* __restrict__ B,
                                                  float* __restrict__ C) {
    __shared__ __align__(16) u16 lAh[128 * 40];
    __shared__ __align__(16) u16 lAl[128 * 40];
    __shared__ __align__(16) u16 lBh[128 * 40];
    __shared__ __align__(16) u16 lBl[128 * 40];
    const int tid  = threadIdx.x;
    const int wave = tid >> 6, lane = tid & 63;
    const int lr = lane & 15, quad = lane >> 4;
    const int waveM = wave >> 1, waveN = wave & 1;
    const int rowBase = blockIdx.y * 128;
    const int colBase = blockIdx.x * 128;
    const int c0r = tid >> 2, c1r = c0r + 64;
    const int ck  = (tid & 3) * 8;

    floatx4 acc[4][4];
#pragma unroll
    for (int mi = 0; mi < 4; mi++)
#pragma unroll
        for (int ni = 0; ni < 4; ni++) acc[mi][ni] = (floatx4)0.0f;

    for (int k0 = 0; k0 < 512; k0 += 32) {
        __syncthreads();
        stage8(&A[(size_t)(rowBase + c0r) * 512 + k0 + ck], &lAh[c0r * 40 + ck], &lAl[c0r * 40 + ck]);
        stage8(&A[(size_t)(rowBase + c1r) * 512 + k0 + ck], &lAh[c1r * 40 + ck], &lAl[c1r * 40 + ck]);
        stage8(&B[(size_t)(colBase + c0r) * 512 + k0 + ck], &lBh[c0r * 40 + ck], &lBl[c0r * 40 + ck]);
        stage8(&B[(size_t)(colBase + c1r) * 512 + k0 + ck], &lBh[c1r * 40 + ck], &lBl[c1r * 40 + ck]);
        __syncthreads();

        bf16x8 afh[4], afl[4], bfh[4], bfl[4];
#pragma unroll
        for (int mi = 0; mi < 4; mi++) {
            int off = (waveM * 64 + mi * 16 + lr) * 40 + quad * 8;
            afh[mi] = *(const bf16x8*)&lAh[off];
            afl[mi] = *(const bf16x8*)&lAl[off];
        }
#pragma unroll
        for (int ni = 0; ni < 4; ni++) {
            int off = (waveN * 64 + ni * 16 + lr) * 40 + quad * 8;
            bfh[ni] = *(const bf16x8*)&lBh[off];
            bfl[ni] = *(const bf16x8*)&lBl[off];
        }
#pragma unroll
        for (int mi = 0; mi < 4; mi++)
#pragma unroll
            for (int ni = 0; ni < 4; ni++) {
                acc[mi][ni] = __builtin_amdgcn_mfma_f32_16x16x32_bf16(afh[mi], bfh[ni], acc[mi][ni], 0, 0, 0);
                acc[mi][ni] = __builtin_amdgcn_mfma_f32_16x16x32_bf16(afh[mi], bfl[ni], acc[mi][ni], 0, 0, 0);
                acc[mi][ni] = __builtin_amdgcn_mfma_f32_16x16x32_bf16(afl[mi], bfh[ni], acc[mi][ni], 0, 0, 0);
            }
    }
#pragma unroll
    for (int mi = 0; mi < 4; mi++)
#pragma unroll
        for (int ni = 0; ni < 4; ni++) {
            int r0 = rowBase + waveM * 64 + mi * 16 + quad * 4;
            int c  = colBase + waveN * 64 + ni * 16 + lr;
#pragma unroll
            for (int r = 0; r < 4; r++)
                C[(size_t)(r0 + r) * 4096 + c] = acc[mi][ni][r];
        }
}

// ---------------------------------------------------------------------------
// In-place transpose (fallback path only).
// ---------------------------------------------------------------------------
__global__ __launch_bounds__(256) void transpose_inplace(float* __restrict__ M) {
    int tr = blockIdx.y, tc = blockIdx.x;
    if (tr > tc) return;
    __shared__ float tA[64 * 65];
    __shared__ float tB[64 * 65];
    int tid = threadIdx.x;
    int tx = tid & 63, ty = tid >> 6;
#pragma unroll
    for (int i = 0; i < 16; i++) {
        int r = i * 4 + ty;
        tA[r * 65 + tx] = M[(size_t)(tr * 64 + r) * 4096 + tc * 64 + tx];
    }
    if (tr != tc) {
#pragma unroll
        for (int i = 0; i < 16; i++) {
            int r = i * 4 + ty;
            tB[r * 65 + tx] = M[(size_t)(tc * 64 + r) * 4096 + tr * 64 + tx];
        }
    }
    __syncthreads();
#pragma unroll
    for (int i = 0; i < 16; i++) {
        int r = i * 4 + ty;
        M[(size_t)(tc * 64 + r) * 4096 + tr * 64 + tx] = tA[tx * 65 + r];
    }
    if (tr != tc) {
#pragma unroll
        for (int i = 0; i < 16; i++) {
            int r = i * 4 + ty;
            M[(size_t)(tr * 64 + r) * 4096 + tc * 64 + tx] = tB[tx * 65 + r];
        }
    }
}

// ---------------------------------------------------------------------------
// Per-row statistics + state update (unchanged from passing round 6).
// ---------------------------------------------------------------------------
__global__ __launch_bounds__(256) void row_process(
    const float* __restrict__ mat,
    const float* __restrict__ tau_in, const float* __restrict__ s_in,
    const float* __restrict__ b_in, const float* __restrict__ u_in,
    const int* __restrict__ ids, const int* __restrict__ epoch_p,
    float* __restrict__ out, float* __restrict__ rowbuf,
    long long n, int side) {
    const int i = blockIdx.x;
    const int tid = threadIdx.x;
    const int lane = tid & 63, wv = tid >> 6;
    const float* row = mat + (size_t)i * 4096;

    float4 v[4];
#pragma unroll
    for (int q = 0; q < 4; q++) v[q] = *(const float4*)&row[4 * (tid + 256 * q)];

    const int id = ids[i];
    const float tau   = tau_in[id];
    const float old_b = b_in[id];
    const float old_s = s_in[id];
    const float old_u = u_in[id];
    const float diag  = row[i];

    __shared__ float sred[8];

    float m = -3.4e38f;
#pragma unroll
    for (int q = 0; q < 4; q++)
        m = fmaxf(m, fmaxf(fmaxf(v[q].x, v[q].y), fmaxf(v[q].z, v[q].w)));
    for (int o = 32; o > 0; o >>= 1) m = fmaxf(m, __shfl_xor(m, o));
    if (lane == 0) sred[wv] = m;
    __syncthreads();
    m = fmaxf(fmaxf(sred[0], sred[1]), fmaxf(sred[2], sred[3]));
    const float b_row = fmaxf((m - diag) / tau, old_b);
    __syncthreads();

    float S0 = 0.f, S1 = 0.f;
#pragma unroll
    for (int q = 0; q < 4; q++) {
        int jb = 4 * (tid + 256 * q);
        float vals[4] = {v[q].x, v[q].y, v[q].z, v[q].w};
#pragma unroll
        for (int e = 0; e < 4; e++) {
            int j = jb + e;
            if (j != i) {
                float idt = (vals[e] - diag) / tau;
                float ex = expf(idt - b_row);
                S0 += ex;
                S1 += idt * ex;
            }
        }
    }
    for (int o = 32; o > 0; o >>= 1) { S0 += __shfl_xor(S0, o); S1 += __shfl_xor(S1, o); }
    if (lane == 0) { sred[wv] = S0; sred[4 + wv] = S1; }
    __syncthreads();

    if (tid == 0) {
        S0 = sred[0] + sred[1] + sred[2] + sred[3];
        S1 = sred[4] + sred[5] + sred[6] + sred[7];
        float g = S0;
        float sI = (*epoch_p == 0) ? g
                 : 0.2f * old_s * expf(old_b - b_row) + 0.8f * g;
        float denom = sI + 1e-10f;
        float wsum = S1 / denom;
        float lossr = tau * wsum;
        float tw = logf(sI * (1.0f / 4095.0f)) + b_row + 8.0f - wsum;
        tw = fminf(fmaxf(tw, -5.0f), 5.0f);
        float uval = 0.5f * old_u + 0.5f * tw;
        float taun = fminf(fmaxf(tau - 1e-5f * uval, 0.005f), 0.05f);

        float* sect = out + 5;
        sect[(size_t)(0 + side) * (size_t)n + id] = sI;
        sect[(size_t)(2 + side) * (size_t)n + id] = b_row;
        sect[(size_t)(4 + side) * (size_t)n + id] = uval;
        sect[(size_t)(6 + side) * (size_t)n + id] = taun;

        rowbuf[(2 * side + 0) * 4096 + i] = lossr;
        rowbuf[(2 * side + 1) * 4096 + i] = tw;
    }
}

// ---------------------------------------------------------------------------
// Bulk copy, vectorized: 3-elem head -> aligned float4 body -> tail.
// dst section start (5 + k*1e6) % 4 == 1, so +3 reaches 16B alignment.
// ---------------------------------------------------------------------------
__global__ __launch_bounds__(256) void copy_all(
    const float* __restrict__ p0, const float* __restrict__ p1,
    const float* __restrict__ p2, const float* __restrict__ p3,
    const float* __restrict__ p4, const float* __restrict__ p5,
    const float* __restrict__ p6, const float* __restrict__ p7,
    float* __restrict__ out, long long n) {
    const float* src;
    switch (blockIdx.y) {
        case 0: src = p0; break; case 1: src = p1; break;
        case 2: src = p2; break; case 3: src = p3; break;
        case 4: src = p4; break; case 5: src = p5; break;
        case 6: src = p6; break; default: src = p7; break;
    }
    float* dst = out + 5 + (size_t)blockIdx.y * (size_t)n;
    const long long m4 = (n - 3) >> 2;   // aligned float4 count
#pragma unroll
    for (int k = 0; k < 2; k++) {
        long long f = (long long)blockIdx.x * 512 + k * 256 + threadIdx.x;
        if (f < m4) {
            long long e = 3 + f * 4;
            float4 vv = {src[e], src[e + 1], src[e + 2], src[e + 3]};
            *(float4*)&dst[e] = vv;
        }
    }
    if (blockIdx.x == 0) {
        int t = threadIdx.x;
        if (t < 3) dst[t] = src[t];
        long long tail0 = 3 + m4 * 4;
        int tcount = (int)(n - tail0);
        if (t >= 3 && t < 3 + tcount) dst[tail0 + (t - 3)] = src[tail0 + (t - 3)];
    }
}

// ---------------------------------------------------------------------------
// Final 5 scalars (proven round 6).
// ---------------------------------------------------------------------------
__global__ __launch_bounds__(256) void scalars(
    const float* __restrict__ rows,
    const float* __restrict__ tau_I, const float* __restrict__ tau_T,
    const int* __restrict__ image_ids, const int* __restrict__ text_ids,
    float* __restrict__ out) {
    int tid = threadIdx.x;
    int lane = tid & 63, wv = tid >> 6;
    float a[6] = {0, 0, 0, 0, 0, 0};
    for (int e = tid; e < 4096; e += 256) {
        a[0] += rows[0 * 4096 + e];
        a[1] += rows[1 * 4096 + e];
        a[2] += rows[2 * 4096 + e];
        a[3] += rows[3 * 4096 + e];
        a[4] += tau_I[image_ids[e]];
        a[5] += tau_T[text_ids[e]];
    }
    __shared__ float sred[4][6];
#pragma unroll
    for (int k = 0; k < 6; k++)
        for (int o = 32; o > 0; o >>= 1) a[k] += __shfl_xor(a[k], o);
    if (lane == 0)
#pragma unroll
        for (int k = 0; k < 6; k++) sred[wv][k] = a[k];
    __syncthreads();
    if (tid == 0) {
#pragma unroll
        for (int k = 0; k < 6; k++)
            a[k] = sred[0][k] + sred[1][k] + sred[2][k] + sred[3][k];
        const float inv = 1.0f / 4096.0f;
        out[0] = (a[0] + a[2]) * inv;
        out[1] = a[4] * inv;
        out[2] = a[5] * inv;
        out[3] = a[1] * inv;
        out[4] = a[3] * inv;
    }
}

extern "C" void kernel_launch(void* const* d_in, const int* in_sizes, int n_in,
                              void* d_out, int out_size, void* d_ws, size_t ws_size,
                              hipStream_t stream) {
    const float* img   = (const float*)d_in[0];
    const float* txt   = (const float*)d_in[1];
    const float* s_I   = (const float*)d_in[2];
    const float* s_T   = (const float*)d_in[3];
    const float* b_I   = (const float*)d_in[4];
    const float* b_T   = (const float*)d_in[5];
    const float* u_I   = (const float*)d_in[6];
    const float* u_T   = (const float*)d_in[7];
    const float* tau_I = (const float*)d_in[8];
    const float* tau_T = (const float*)d_in[9];
    const int* image_ids = (const int*)d_in[10];
    const int* text_ids  = (const int*)d_in[11];
    const int* epoch     = (const int*)d_in[12];
    float* out = (float*)d_out;
    const long long n = in_sizes[2];   // 1,000,000
    const int nfeat = in_sizes[0];     // 4096*512

    const size_t MB = 1024 * 1024;
    const size_t need_fast = 144 * MB + 64 * 1024;

    if (ws_size >= need_fast) {
        // FAST: splits [0,16MB) | sim [16,80) | simT [80,144) | rowbuf @144MB
        u16* Ah = (u16*)d_ws;
        u16* Al = Ah + (size_t)nfeat;
        u16* Bh = Al + (size_t)nfeat;
        u16* Bl = Bh + (size_t)nfeat;
        float* sim  = (float*)((char*)d_ws + 16 * MB);
        float* simT = (float*)((char*)d_ws + 80 * MB);
        float* rows = (float*)((char*)d_ws + 144 * MB);

        presplit<<<dim3((nfeat / 8 + 255) / 256, 2), 256, 0, stream>>>(
            img, txt, Ah, Al, Bh, Bl, nfeat);

        gemm_dma<<<dim3(32, 32), 256, 0, stream>>>(Ah, Al, Bh, Bl, sim, simT);

        copy_all<<<dim3((int)(((n - 3) / 4 + 511) / 512), 8), 256, 0, stream>>>(
            s_I, s_T, b_I, b_T, u_I, u_T, tau_I, tau_T, out, n);

        row_process<<<4096, 256, 0, stream>>>(
            sim, tau_I, s_I, b_I, u_I, image_ids, epoch, out, rows, n, 0);
        row_process<<<4096, 256, 0, stream>>>(
            simT, tau_T, s_T, b_T, u_T, text_ids, epoch, out, rows, n, 1);

        scalars<<<1, 256, 0, stream>>>(rows, tau_I, tau_T, image_ids, text_ids, out);
    } else {
        // FALLBACK (round-6 proven): sim [0,64MB) | rowbuf @64MB
        float* sim  = (float*)d_ws;
        float* rows = (float*)((char*)d_ws + 64 * MB);

        gemm_split<<<dim3(32, 32), 256, 0, stream>>>(img, txt, sim);

        copy_all<<<dim3((int)(((n - 3) / 4 + 511) / 512), 8), 256, 0, stream>>>(
            s_I, s_T, b_I, b_T, u_I, u_T, tau_I, tau_T, out, n);

        row_process<<<4096, 256, 0, stream>>>(
            sim, tau_I, s_I, b_I, u_I, image_ids, epoch, out, rows, n, 0);

        transpose_inplace<<<dim3(64, 64), 256, 0, stream>>>(sim);

        row_process<<<4096, 256, 0, stream>>>(
            sim, tau_T, s_T, b_T, u_T, text_ids, epoch, out, rows, n, 1);

        scalars<<<1, 256, 0, stream>>>(rows, tau_I, tau_T, image_ids, text_ids, out);
    }
}

// Round 8
// 230.015 us; speedup vs baseline: 1.1233x; 1.0346x over previous
//
#include <hip/hip_runtime.h>

typedef unsigned short u16;
typedef unsigned int u32;

typedef __bf16 bf16x8 __attribute__((ext_vector_type(8)));
typedef float floatx4 __attribute__((ext_vector_type(4)));

__device__ __forceinline__ u16 f2bf(float f) {
    union { float f; u32 u; } c; c.f = f;
    u32 u = c.u;
    u32 r = u + 0x7FFFu + ((u >> 16) & 1u);   // round-to-nearest-even
    return (u16)(r >> 16);
}
__device__ __forceinline__ float bf2f(u16 x) {
    union { u32 u; float f; } c; c.u = ((u32)x) << 16; return c.f;
}

// async global->LDS DMA, 16B per lane; lds base must be wave-uniform
__device__ __forceinline__ void dma16(const u16* g, u16* l) {
#if __has_builtin(__builtin_amdgcn_global_load_lds)
    __builtin_amdgcn_global_load_lds(
        (const __attribute__((address_space(1))) u32*)g,
        (__attribute__((address_space(3))) u32*)l, 16, 0, 0);
#else
    int lane = threadIdx.x & 63;
    *(uint4*)(l + lane * 8) = *(const uint4*)(g);
#endif
}

// ---------------------------------------------------------------------------
// One-shot split: f32 features -> bf16 hi/lo arrays (linear layout).
// ---------------------------------------------------------------------------
__global__ __launch_bounds__(256) void presplit(
    const float* __restrict__ a, const float* __restrict__ b,
    u16* __restrict__ Ah, u16* __restrict__ Al,
    u16* __restrict__ Bh, u16* __restrict__ Bl, int n) {
    const float* src = blockIdx.y ? b : a;
    u16* dh = blockIdx.y ? Bh : Ah;
    u16* dl = blockIdx.y ? Bl : Al;
    int i = (blockIdx.x * 256 + threadIdx.x) * 8;
    if (i >= n) return;
    float4 v0 = *(const float4*)&src[i];
    float4 v1 = *(const float4*)&src[i + 4];
    float xs[8] = {v0.x, v0.y, v0.z, v0.w, v1.x, v1.y, v1.z, v1.w};
    u16 h[8], l[8];
#pragma unroll
    for (int e = 0; e < 8; e++) {
        h[e] = f2bf(xs[e]);
        l[e] = f2bf(xs[e] - bf2f(h[e]));
    }
    *(uint4*)&dh[i] = *(uint4*)h;
    *(uint4*)&dl[i] = *(uint4*)l;
}

// ---------------------------------------------------------------------------
// FUSED: blocks [0,1024) run the split-precision GEMM (sim + simT outputs);
// blocks [1024, 1024+2048) bulk-copy the 8 f32 state arrays into d_out.
// The copy is pure-memory and overlaps the latency-bound GEMM's idle slots.
// ---------------------------------------------------------------------------
#define COPY_BLOCKS 2048

__global__ __launch_bounds__(256) void gemm_copy(
    const u16* __restrict__ Ah, const u16* __restrict__ Al,
    const u16* __restrict__ Bh, const u16* __restrict__ Bl,
    float* __restrict__ sim, float* __restrict__ simT,
    const float* __restrict__ p0, const float* __restrict__ p1,
    const float* __restrict__ p2, const float* __restrict__ p3,
    const float* __restrict__ p4, const float* __restrict__ p5,
    const float* __restrict__ p6, const float* __restrict__ p7,
    float* __restrict__ out, long long n) {
    __shared__ __align__(16) u16 sAh[128 * 32];
    __shared__ __align__(16) u16 sAl[128 * 32];
    __shared__ __align__(16) u16 sBh[128 * 32];
    __shared__ __align__(16) u16 sBl[128 * 32];

    const int bid = blockIdx.x;
    if (bid >= 1024) {
        // ------------------ copy part ------------------
        const int cb = bid - 1024;
        const float* srcs[8] = {p0, p1, p2, p3, p4, p5, p6, p7};
        const long long total = 8 * n;
        const long long G = (total - 3) >> 2;   // dest-aligned float4 groups
        for (long long g = (long long)cb * 256 + threadIdx.x; g < G;
             g += (long long)COPY_BLOCKS * 256) {
            long long e = 3 + 4 * g;            // flat src index of group start
            int k = (int)(e / n);
            long long bound = (long long)(k + 1) * n;
            float vv[4];
#pragma unroll
            for (int j = 0; j < 4; j++) {
                long long ee = e + j;
                int kk = (ee >= bound) ? k + 1 : k;
                vv[j] = srcs[kk][ee - (long long)kk * n];
            }
            float4 q = {vv[0], vv[1], vv[2], vv[3]};
            *(float4*)&out[5 + e] = q;          // 5+e = 8+4g -> 16B aligned
        }
        if (cb == 0) {
            int t = threadIdx.x;
            long long tail0 = 3 + 4 * G;
            int tcount = (int)(total - tail0);  // 0..3
            long long e = -1;
            if (t < 3) e = t;                                   // head 0,1,2
            else if (t < 3 + tcount) e = tail0 + (t - 3);       // tail
            if (e >= 0) {
                int k = (int)(e / n);
                out[5 + e] = srcs[k][e - (long long)k * n];
            }
        }
        return;
    }

    // ------------------ GEMM part ------------------
    const int tid  = threadIdx.x;
    const int wave = tid >> 6, lane = tid & 63;
    const int lr = lane & 15, quad = lane >> 4;
    const int waveM = wave >> 1, waveN = wave & 1;
    const int rowBase = (bid >> 5) * 128;
    const int colBase = (bid & 31) * 128;

    const int o0 = wave * 1024 + lane * 16;
    const int o1 = o0 + 4096;
    const int r0s = o0 >> 6, c0s = (o0 & 63) >> 1;
    const int r1s = o1 >> 6, c1s = (o1 & 63) >> 1;
    const int l0 = wave * 512;
    const int l1 = wave * 512 + 2048;

    floatx4 acc[4][4];
#pragma unroll
    for (int mi = 0; mi < 4; mi++)
#pragma unroll
        for (int ni = 0; ni < 4; ni++) acc[mi][ni] = (floatx4)0.0f;

    for (int k0 = 0; k0 < 512; k0 += 32) {
        __syncthreads();
        dma16(&Ah[(size_t)(rowBase + r0s) * 512 + k0 + c0s], sAh + l0);
        dma16(&Ah[(size_t)(rowBase + r1s) * 512 + k0 + c1s], sAh + l1);
        dma16(&Al[(size_t)(rowBase + r0s) * 512 + k0 + c0s], sAl + l0);
        dma16(&Al[(size_t)(rowBase + r1s) * 512 + k0 + c1s], sAl + l1);
        dma16(&Bh[(size_t)(colBase + r0s) * 512 + k0 + c0s], sBh + l0);
        dma16(&Bh[(size_t)(colBase + r1s) * 512 + k0 + c1s], sBh + l1);
        dma16(&Bl[(size_t)(colBase + r0s) * 512 + k0 + c0s], sBl + l0);
        dma16(&Bl[(size_t)(colBase + r1s) * 512 + k0 + c1s], sBl + l1);
        __syncthreads();

        bf16x8 afh[4], afl[4], bfh[4], bfl[4];
#pragma unroll
        for (int mi = 0; mi < 4; mi++) {
            int off = (waveM * 64 + mi * 16 + lr) * 32 + quad * 8;
            afh[mi] = *(const bf16x8*)&sAh[off];
            afl[mi] = *(const bf16x8*)&sAl[off];
        }
#pragma unroll
        for (int ni = 0; ni < 4; ni++) {
            int off = (waveN * 64 + ni * 16 + lr) * 32 + quad * 8;
            bfh[ni] = *(const bf16x8*)&sBh[off];
            bfl[ni] = *(const bf16x8*)&sBl[off];
        }
#pragma unroll
        for (int mi = 0; mi < 4; mi++)
#pragma unroll
            for (int ni = 0; ni < 4; ni++) {
                acc[mi][ni] = __builtin_amdgcn_mfma_f32_16x16x32_bf16(afh[mi], bfh[ni], acc[mi][ni], 0, 0, 0);
                acc[mi][ni] = __builtin_amdgcn_mfma_f32_16x16x32_bf16(afh[mi], bfl[ni], acc[mi][ni], 0, 0, 0);
                acc[mi][ni] = __builtin_amdgcn_mfma_f32_16x16x32_bf16(afl[mi], bfh[ni], acc[mi][ni], 0, 0, 0);
            }
    }

    // C/D layout: col = lane&15, row = (lane>>4)*4 + reg  [m89/m91 verified]
#pragma unroll
    for (int mi = 0; mi < 4; mi++)
#pragma unroll
        for (int ni = 0; ni < 4; ni++) {
            int rr = rowBase + waveM * 64 + mi * 16 + quad * 4;
            int cc = colBase + waveN * 64 + ni * 16 + lr;
#pragma unroll
            for (int r = 0; r < 4; r++)
                sim[(size_t)(rr + r) * 4096 + cc] = acc[mi][ni][r];
            float4 tv = {acc[mi][ni][0], acc[mi][ni][1], acc[mi][ni][2], acc[mi][ni][3]};
            *(float4*)&simT[(size_t)cc * 4096 + rr] = tv;   // rr%4==0 -> aligned
        }
}

// ---------------------------------------------------------------------------
// Both row passes in ONE dispatch: blocks [0,4096) = image side on sim,
// blocks [4096,8192) = text side on simT. Body identical to proven round 6.
// ---------------------------------------------------------------------------
struct RowsArgs {
    const float* sim;
    const float* simT;
    const float* tauI; const float* sI; const float* bI; const float* uI;
    const float* tauT; const float* sT; const float* bT; const float* uT;
    const int* img_ids; const int* txt_ids; const int* epoch_p;
    float* out; float* rowbuf; long long n;
};

__global__ __launch_bounds__(256) void rows_both(RowsArgs a) {
    const int bid = blockIdx.x;
    const int side = bid >> 12;
    const int i = bid & 4095;
    const float* mat    = side ? a.simT : a.sim;
    const float* tau_in = side ? a.tauT : a.tauI;
    const float* s_in   = side ? a.sT   : a.sI;
    const float* b_in   = side ? a.bT   : a.bI;
    const float* u_in   = side ? a.uT   : a.uI;
    const int*   ids    = side ? a.txt_ids : a.img_ids;

    const int tid = threadIdx.x;
    const int lane = tid & 63, wv = tid >> 6;
    const float* row = mat + (size_t)i * 4096;

    float4 v[4];
#pragma unroll
    for (int q = 0; q < 4; q++) v[q] = *(const float4*)&row[4 * (tid + 256 * q)];

    const int id = ids[i];
    const float tau   = tau_in[id];
    const float old_b = b_in[id];
    const float old_s = s_in[id];
    const float old_u = u_in[id];
    const float diag  = row[i];

    __shared__ float sred[8];

    // pass 1: row max (includes diagonal, as reference does)
    float m = -3.4e38f;
#pragma unroll
    for (int q = 0; q < 4; q++)
        m = fmaxf(m, fmaxf(fmaxf(v[q].x, v[q].y), fmaxf(v[q].z, v[q].w)));
    for (int o = 32; o > 0; o >>= 1) m = fmaxf(m, __shfl_xor(m, o));
    if (lane == 0) sred[wv] = m;
    __syncthreads();
    m = fmaxf(fmaxf(sred[0], sred[1]), fmaxf(sred[2], sred[3]));
    const float b_row = fmaxf((m - diag) / tau, old_b);
    __syncthreads();

    // pass 2: S0 = sum exp(idt-b), S1 = sum idt*exp(idt-b), over j != i
    float S0 = 0.f, S1 = 0.f;
#pragma unroll
    for (int q = 0; q < 4; q++) {
        int jb = 4 * (tid + 256 * q);
        float vals[4] = {v[q].x, v[q].y, v[q].z, v[q].w};
#pragma unroll
        for (int e = 0; e < 4; e++) {
            int j = jb + e;
            if (j != i) {
                float idt = (vals[e] - diag) / tau;
                float ex = expf(idt - b_row);
                S0 += ex;
                S1 += idt * ex;
            }
        }
    }
    for (int o = 32; o > 0; o >>= 1) { S0 += __shfl_xor(S0, o); S1 += __shfl_xor(S1, o); }
    if (lane == 0) { sred[wv] = S0; sred[4 + wv] = S1; }
    __syncthreads();

    if (tid == 0) {
        S0 = sred[0] + sred[1] + sred[2] + sred[3];
        S1 = sred[4] + sred[5] + sred[6] + sred[7];
        float g = S0;
        float sI = (*a.epoch_p == 0) ? g
                 : 0.2f * old_s * expf(old_b - b_row) + 0.8f * g;
        float denom = sI + 1e-10f;
        float wsum = S1 / denom;
        float lossr = tau * wsum;
        float tw = logf(sI * (1.0f / 4095.0f)) + b_row + 8.0f - wsum;
        tw = fminf(fmaxf(tw, -5.0f), 5.0f);
        float uval = 0.5f * old_u + 0.5f * tw;
        float taun = fminf(fmaxf(tau - 1e-5f * uval, 0.005f), 0.05f);

        float* sect = a.out + 5;
        sect[(size_t)(0 + side) * (size_t)a.n + id] = sI;
        sect[(size_t)(2 + side) * (size_t)a.n + id] = b_row;
        sect[(size_t)(4 + side) * (size_t)a.n + id] = uval;
        sect[(size_t)(6 + side) * (size_t)a.n + id] = taun;

        a.rowbuf[(2 * side + 0) * 4096 + i] = lossr;
        a.rowbuf[(2 * side + 1) * 4096 + i] = tw;
    }
}

// ---------------------------------------------------------------------------
// Final 5 scalars (proven round 6).
// ---------------------------------------------------------------------------
__global__ __launch_bounds__(256) void scalars(
    const float* __restrict__ rows,
    const float* __restrict__ tau_I, const float* __restrict__ tau_T,
    const int* __restrict__ image_ids, const int* __restrict__ text_ids,
    float* __restrict__ out) {
    int tid = threadIdx.x;
    int lane = tid & 63, wv = tid >> 6;
    float a[6] = {0, 0, 0, 0, 0, 0};
    for (int e = tid; e < 4096; e += 256) {
        a[0] += rows[0 * 4096 + e];
        a[1] += rows[1 * 4096 + e];
        a[2] += rows[2 * 4096 + e];
        a[3] += rows[3 * 4096 + e];
        a[4] += tau_I[image_ids[e]];
        a[5] += tau_T[text_ids[e]];
    }
    __shared__ float sred[4][6];
#pragma unroll
    for (int k = 0; k < 6; k++)
        for (int o = 32; o > 0; o >>= 1) a[k] += __shfl_xor(a[k], o);
    if (lane == 0)
#pragma unroll
        for (int k = 0; k < 6; k++) sred[wv][k] = a[k];
    __syncthreads();
    if (tid == 0) {
#pragma unroll
        for (int k = 0; k < 6; k++)
            a[k] = sred[0][k] + sred[1][k] + sred[2][k] + sred[3][k];
        const float inv = 1.0f / 4096.0f;
        out[0] = (a[0] + a[2]) * inv;
        out[1] = a[4] * inv;
        out[2] = a[5] * inv;
        out[3] = a[1] * inv;
        out[4] = a[3] * inv;
    }
}

extern "C" void kernel_launch(void* const* d_in, const int* in_sizes, int n_in,
                              void* d_out, int out_size, void* d_ws, size_t ws_size,
                              hipStream_t stream) {
    const float* img   = (const float*)d_in[0];
    const float* txt   = (const float*)d_in[1];
    const float* s_I   = (const float*)d_in[2];
    const float* s_T   = (const float*)d_in[3];
    const float* b_I   = (const float*)d_in[4];
    const float* b_T   = (const float*)d_in[5];
    const float* u_I   = (const float*)d_in[6];
    const float* u_T   = (const float*)d_in[7];
    const float* tau_I = (const float*)d_in[8];
    const float* tau_T = (const float*)d_in[9];
    const int* image_ids = (const int*)d_in[10];
    const int* text_ids  = (const int*)d_in[11];
    const int* epoch     = (const int*)d_in[12];
    float* out = (float*)d_out;
    const long long n = in_sizes[2];   // 1,000,000
    const int nfeat = in_sizes[0];     // 4096*512

    const size_t MB = 1024 * 1024;
    // ws (>=144MB proven round 7): splits [0,16MB) | sim [16,80) | simT [80,144)
    // rowbuf overlays the splits region (dead after gemm; stream-serial).
    u16* Ah = (u16*)d_ws;
    u16* Al = Ah + (size_t)nfeat;
    u16* Bh = Al + (size_t)nfeat;
    u16* Bl = Bh + (size_t)nfeat;
    float* sim  = (float*)((char*)d_ws + 16 * MB);
    float* simT = (float*)((char*)d_ws + 80 * MB);
    float* rows = (float*)d_ws;        // 4 x 4096 f32, overlays splits

    presplit<<<dim3((nfeat / 8 + 255) / 256, 2), 256, 0, stream>>>(
        img, txt, Ah, Al, Bh, Bl, nfeat);

    gemm_copy<<<1024 + COPY_BLOCKS, 256, 0, stream>>>(
        Ah, Al, Bh, Bl, sim, simT,
        s_I, s_T, b_I, b_T, u_I, u_T, tau_I, tau_T, out, n);

    RowsArgs a;
    a.sim = sim; a.simT = simT;
    a.tauI = tau_I; a.sI = s_I; a.bI = b_I; a.uI = u_I;
    a.tauT = tau_T; a.sT = s_T; a.bT = b_T; a.uT = u_T;
    a.img_ids = image_ids; a.txt_ids = text_ids; a.epoch_p = epoch;
    a.out = out; a.rowbuf = rows; a.n = n;
    rows_both<<<8192, 256, 0, stream>>>(a);

    scalars<<<1, 256, 0, stream>>>(rows, tau_I, tau_T, image_ids, text_ids, out);
}

// Round 9
// 210.323 us; speedup vs baseline: 1.2285x; 1.0936x over previous
//
#include <hip/hip_runtime.h>

typedef unsigned short u16;
typedef unsigned int u32;

typedef __bf16 bf16x8 __attribute__((ext_vector_type(8)));
typedef float floatx4 __attribute__((ext_vector_type(4)));

__device__ __forceinline__ u16 f2bf(float f) {
    union { float f; u32 u; } c; c.f = f;
    u32 u = c.u;
    u32 r = u + 0x7FFFu + ((u >> 16) & 1u);   // round-to-nearest-even
    return (u16)(r >> 16);
}
__device__ __forceinline__ float bf2f(u16 x) {
    union { u32 u; float f; } c; c.u = ((u32)x) << 16; return c.f;
}

// online-softmax partial combine: (M,P0,P1) += (m,p0,p1)
// P0 = sum exp(y-M), P1 = sum y*exp(y-M)
__device__ __forceinline__ void comb(float& M, float& P0, float& P1,
                                     float m, float p0, float p1) {
    float nm = fmaxf(M, m);
    float s = __expf(M - nm), t = __expf(m - nm);
    P0 = P0 * s + p0 * t;
    P1 = P1 * s + p1 * t;
    M = nm;
}

// async global->LDS DMA, 16B per lane; lds base must be wave-uniform
__device__ __forceinline__ void dma16(const u16* g, u16* l) {
#if __has_builtin(__builtin_amdgcn_global_load_lds)
    __builtin_amdgcn_global_load_lds(
        (const __attribute__((address_space(1))) u32*)g,
        (__attribute__((address_space(3))) u32*)l, 16, 0, 0);
#else
    int lane = threadIdx.x & 63;
    *(uint4*)(l + lane * 8) = *(const uint4*)(g);
#endif
}

// ---------------------------------------------------------------------------
// presplit: f32 features -> bf16 hi/lo arrays; first 16 x-blocks also gather
// taur[i] = tau_I[image_ids[i]], tauc[j] = tau_T[text_ids[j]].
// ---------------------------------------------------------------------------
__global__ __launch_bounds__(256) void presplit(
    const float* __restrict__ a, const float* __restrict__ b,
    u16* __restrict__ Ah, u16* __restrict__ Al,
    u16* __restrict__ Bh, u16* __restrict__ Bl, int n,
    const float* __restrict__ tauI, const float* __restrict__ tauT,
    const int* __restrict__ img_ids, const int* __restrict__ txt_ids,
    float* __restrict__ taur, float* __restrict__ tauc) {
    if (blockIdx.y == 0 && blockIdx.x < 16) {
        int t = blockIdx.x * 256 + threadIdx.x;   // 0..4095
        taur[t] = tauI[img_ids[t]];
        tauc[t] = tauT[txt_ids[t]];
    }
    const float* src = blockIdx.y ? b : a;
    u16* dh = blockIdx.y ? Bh : Ah;
    u16* dl = blockIdx.y ? Bl : Al;
    int i = (blockIdx.x * 256 + threadIdx.x) * 8;
    if (i >= n) return;
    float4 v0 = *(const float4*)&src[i];
    float4 v1 = *(const float4*)&src[i + 4];
    float xs[8] = {v0.x, v0.y, v0.z, v0.w, v1.x, v1.y, v1.z, v1.w};
    u16 h[8], l[8];
#pragma unroll
    for (int e = 0; e < 8; e++) {
        h[e] = f2bf(xs[e]);
        l[e] = f2bf(xs[e] - bf2f(h[e]));
    }
    *(uint4*)&dh[i] = *(uint4*)h;
    *(uint4*)&dl[i] = *(uint4*)l;
}

// ---------------------------------------------------------------------------
// FUSED flash-GEMM + state copy.
// Blocks [0,1024): 128x128 sim tile via split bf16 MFMA; epilogue reduces the
//   tile to per-row / per-column online-softmax partials (m,P0,P1) of
//   y = sim/tau, writes 3 floats per (row,coltile) and (col,rowtile), plus
//   the raw diagonal. NO sim matrix is materialized.
// Blocks [1024,3072): bulk-copy the 8 f32 state arrays into d_out.
// ---------------------------------------------------------------------------
#define COPY_BLOCKS 2048

__global__ __launch_bounds__(256) void gemm_flash(
    const u16* __restrict__ Ah, const u16* __restrict__ Al,
    const u16* __restrict__ Bh, const u16* __restrict__ Bl,
    const float* __restrict__ taur, const float* __restrict__ tauc,
    float* __restrict__ rowpart, float* __restrict__ colpart,
    float* __restrict__ diag,
    const float* __restrict__ p0, const float* __restrict__ p1,
    const float* __restrict__ p2, const float* __restrict__ p3,
    const float* __restrict__ p4, const float* __restrict__ p5,
    const float* __restrict__ p6, const float* __restrict__ p7,
    float* __restrict__ out, long long n) {
    __shared__ __align__(16) u16 sAh[128 * 32];
    __shared__ __align__(16) u16 sAl[128 * 32];
    __shared__ __align__(16) u16 sBh[128 * 32];
    __shared__ __align__(16) u16 sBl[128 * 32];
    __shared__ float redbuf[1536];   // rows [0,768): (128 rows x 2 waveN x 3)
                                     // cols [768,1536)

    const int bid = blockIdx.x;
    if (bid >= 1024) {
        // ------------------ copy part ------------------
        const int cb = bid - 1024;
        const float* srcs[8] = {p0, p1, p2, p3, p4, p5, p6, p7};
        const long long total = 8 * n;
        const long long G = (total - 3) >> 2;
        for (long long g = (long long)cb * 256 + threadIdx.x; g < G;
             g += (long long)COPY_BLOCKS * 256) {
            long long e = 3 + 4 * g;
            int k = (int)(e / n);
            long long bound = (long long)(k + 1) * n;
            float vv[4];
#pragma unroll
            for (int j = 0; j < 4; j++) {
                long long ee = e + j;
                int kk = (ee >= bound) ? k + 1 : k;
                vv[j] = srcs[kk][ee - (long long)kk * n];
            }
            float4 q = {vv[0], vv[1], vv[2], vv[3]};
            *(float4*)&out[5 + e] = q;
        }
        if (cb == 0) {
            int t = threadIdx.x;
            long long tail0 = 3 + 4 * G;
            int tcount = (int)(total - tail0);
            long long e = -1;
            if (t < 3) e = t;
            else if (t < 3 + tcount) e = tail0 + (t - 3);
            if (e >= 0) {
                int k = (int)(e / n);
                out[5 + e] = srcs[k][e - (long long)k * n];
            }
        }
        return;
    }

    // ------------------ GEMM part ------------------
    const int tid  = threadIdx.x;
    const int wave = tid >> 6, lane = tid & 63;
    const int lr = lane & 15, quad = lane >> 4;
    const int waveM = wave >> 1, waveN = wave & 1;
    const int rowtile = bid >> 5, coltile = bid & 31;
    const int rowBase = rowtile * 128;
    const int colBase = coltile * 128;

    const int o0 = wave * 1024 + lane * 16;
    const int o1 = o0 + 4096;
    const int r0s = o0 >> 6, c0s = (o0 & 63) >> 1;
    const int r1s = o1 >> 6, c1s = (o1 & 63) >> 1;
    const int l0 = wave * 512;
    const int l1 = wave * 512 + 2048;

    floatx4 acc[4][4];
#pragma unroll
    for (int mi = 0; mi < 4; mi++)
#pragma unroll
        for (int ni = 0; ni < 4; ni++) acc[mi][ni] = (floatx4)0.0f;

    for (int k0 = 0; k0 < 512; k0 += 32) {
        __syncthreads();
        dma16(&Ah[(size_t)(rowBase + r0s) * 512 + k0 + c0s], sAh + l0);
        dma16(&Ah[(size_t)(rowBase + r1s) * 512 + k0 + c1s], sAh + l1);
        dma16(&Al[(size_t)(rowBase + r0s) * 512 + k0 + c0s], sAl + l0);
        dma16(&Al[(size_t)(rowBase + r1s) * 512 + k0 + c1s], sAl + l1);
        dma16(&Bh[(size_t)(colBase + r0s) * 512 + k0 + c0s], sBh + l0);
        dma16(&Bh[(size_t)(colBase + r1s) * 512 + k0 + c1s], sBh + l1);
        dma16(&Bl[(size_t)(colBase + r0s) * 512 + k0 + c0s], sBl + l0);
        dma16(&Bl[(size_t)(colBase + r1s) * 512 + k0 + c1s], sBl + l1);
        __syncthreads();

        bf16x8 afh[4], afl[4], bfh[4], bfl[4];
#pragma unroll
        for (int mi = 0; mi < 4; mi++) {
            int off = (waveM * 64 + mi * 16 + lr) * 32 + quad * 8;
            afh[mi] = *(const bf16x8*)&sAh[off];
            afl[mi] = *(const bf16x8*)&sAl[off];
        }
#pragma unroll
        for (int ni = 0; ni < 4; ni++) {
            int off = (waveN * 64 + ni * 16 + lr) * 32 + quad * 8;
            bfh[ni] = *(const bf16x8*)&sBh[off];
            bfl[ni] = *(const bf16x8*)&sBl[off];
        }
#pragma unroll
        for (int mi = 0; mi < 4; mi++)
#pragma unroll
            for (int ni = 0; ni < 4; ni++) {
                acc[mi][ni] = __builtin_amdgcn_mfma_f32_16x16x32_bf16(afh[mi], bfh[ni], acc[mi][ni], 0, 0, 0);
                acc[mi][ni] = __builtin_amdgcn_mfma_f32_16x16x32_bf16(afh[mi], bfl[ni], acc[mi][ni], 0, 0, 0);
                acc[mi][ni] = __builtin_amdgcn_mfma_f32_16x16x32_bf16(afl[mi], bfh[ni], acc[mi][ni], 0, 0, 0);
            }
    }

    // --- epilogue ---
    // C/D layout: v(rr,cc): rr = rowBase+waveM*64+mi*16+quad*4+r,
    //                       cc = colBase+waveN*64+ni*16+lr   [m89/m91]

    // diagonal capture (raw sim value)
    if (rowtile == coltile && waveM == waveN) {
#pragma unroll
        for (int mi = 0; mi < 4; mi++)
#pragma unroll
            for (int r = 0; r < 4; r++)
                if (lr == quad * 4 + r)
                    diag[colBase + waveN * 64 + mi * 16 + lr] = acc[mi][mi][r];
    }

    // row partials (image side): y = v / taur[row], reduce over 128 cols
#pragma unroll
    for (int mi = 0; mi < 4; mi++) {
#pragma unroll
        for (int r = 0; r < 4; r++) {
            int row_local = waveM * 64 + mi * 16 + quad * 4 + r;
            float it = 1.0f / taur[rowBase + row_local];
            float M = -3.4e38f, P0 = 0.f, P1 = 0.f;
#pragma unroll
            for (int ni = 0; ni < 4; ni++) {
                float y = acc[mi][ni][r] * it;
                comb(M, P0, P1, y, 1.0f, y);
            }
#pragma unroll
            for (int mask = 1; mask <= 8; mask <<= 1) {
                float om = __shfl_xor(M, mask);
                float o0 = __shfl_xor(P0, mask);
                float o1 = __shfl_xor(P1, mask);
                comb(M, P0, P1, om, o0, o1);
            }
            if (lr == 0) {
                int x = (row_local * 2 + waveN) * 3;
                redbuf[x] = M; redbuf[x + 1] = P0; redbuf[x + 2] = P1;
            }
        }
    }

    // col partials (text side): y = v / tauc[col], reduce over 128 rows
#pragma unroll
    for (int ni = 0; ni < 4; ni++) {
        int col_local = waveN * 64 + ni * 16 + lr;
        float it = 1.0f / tauc[colBase + col_local];
        float M = -3.4e38f, P0 = 0.f, P1 = 0.f;
#pragma unroll
        for (int mi = 0; mi < 4; mi++)
#pragma unroll
            for (int r = 0; r < 4; r++) {
                float y = acc[mi][ni][r] * it;
                comb(M, P0, P1, y, 1.0f, y);
            }
#pragma unroll
        for (int mask = 16; mask <= 32; mask <<= 1) {
            float om = __shfl_xor(M, mask);
            float o0 = __shfl_xor(P0, mask);
            float o1 = __shfl_xor(P1, mask);
            comb(M, P0, P1, om, o0, o1);
        }
        if (quad == 0) {
            int x = 768 + (col_local * 2 + waveM) * 3;
            redbuf[x] = M; redbuf[x + 1] = P0; redbuf[x + 2] = P1;
        }
    }
    __syncthreads();

    if (tid < 128) {
        int x = tid * 6;
        float M = redbuf[x], P0 = redbuf[x + 1], P1 = redbuf[x + 2];
        comb(M, P0, P1, redbuf[x + 3], redbuf[x + 4], redbuf[x + 5]);
        float* dst = &rowpart[(size_t)(rowBase + tid) * 96 + coltile * 3];
        dst[0] = M; dst[1] = P0; dst[2] = P1;
    } else {
        int c = tid - 128;
        int x = 768 + c * 6;
        float M = redbuf[x], P0 = redbuf[x + 1], P1 = redbuf[x + 2];
        comb(M, P0, P1, redbuf[x + 3], redbuf[x + 4], redbuf[x + 5]);
        float* dst = &colpart[(size_t)(colBase + c) * 96 + rowtile * 3];
        dst[0] = M; dst[1] = P0; dst[2] = P1;
    }
}

// ---------------------------------------------------------------------------
// Final per-row/col state update from partials. One thread per (side,row).
// S0 = P0*e - exp(-b), S1 = (P1 - y_ii*P0)*e, e = exp(M - y_ii - b),
// b = max(M - y_ii, old_b), y_ii = diag/tau.
// ---------------------------------------------------------------------------
struct FinArgs {
    const float* rowpart; const float* colpart; const float* diag;
    const float* tauI; const float* sI; const float* bI; const float* uI;
    const float* tauT; const float* sT; const float* bT; const float* uT;
    const int* img_ids; const int* txt_ids; const int* epoch_p;
    float* out; float* rowbuf; long long n;
};

__global__ __launch_bounds__(256) void rows_final(FinArgs a) {
    int t = blockIdx.x * 256 + threadIdx.x;   // 8192 threads
    int side = t >> 12, i = t & 4095;
    const float* part   = side ? a.colpart : a.rowpart;
    const int*   ids    = side ? a.txt_ids : a.img_ids;
    const float* tau_in = side ? a.tauT : a.tauI;
    const float* s_in   = side ? a.sT   : a.sI;
    const float* b_in   = side ? a.bT   : a.bI;
    const float* u_in   = side ? a.uT   : a.uI;

    const float* p = part + (size_t)i * 96;
    float M = -3.4e38f, P0 = 0.f, P1 = 0.f;
#pragma unroll 4
    for (int k = 0; k < 32; k++)
        comb(M, P0, P1, p[3 * k], p[3 * k + 1], p[3 * k + 2]);

    const int id = ids[i];
    const float tau   = tau_in[id];
    const float old_b = b_in[id];
    const float old_s = s_in[id];
    const float old_u = u_in[id];
    const float y_ii  = a.diag[i] / tau;

    float b_row = fmaxf(M - y_ii, old_b);
    float e  = expf(M - y_ii - b_row);
    float S0 = P0 * e - expf(-b_row);           // mask diagonal term
    float S1 = (P1 - y_ii * P0) * e;            // diagonal contributes 0

    float g = S0;
    float sI = (*a.epoch_p == 0) ? g
             : 0.2f * old_s * expf(old_b - b_row) + 0.8f * g;
    float denom = sI + 1e-10f;
    float wsum = S1 / denom;
    float lossr = tau * wsum;
    float tw = logf(sI * (1.0f / 4095.0f)) + b_row + 8.0f - wsum;
    tw = fminf(fmaxf(tw, -5.0f), 5.0f);
    float uval = 0.5f * old_u + 0.5f * tw;
    float taun = fminf(fmaxf(tau - 1e-5f * uval, 0.005f), 0.05f);

    float* sect = a.out + 5;
    sect[(size_t)(0 + side) * (size_t)a.n + id] = sI;
    sect[(size_t)(2 + side) * (size_t)a.n + id] = b_row;
    sect[(size_t)(4 + side) * (size_t)a.n + id] = uval;
    sect[(size_t)(6 + side) * (size_t)a.n + id] = taun;

    a.rowbuf[(2 * side + 0) * 4096 + i] = lossr;
    a.rowbuf[(2 * side + 1) * 4096 + i] = tw;
}

// ---------------------------------------------------------------------------
// Final 5 scalars (proven round 6).
// ---------------------------------------------------------------------------
__global__ __launch_bounds__(256) void scalars(
    const float* __restrict__ rows,
    const float* __restrict__ tau_I, const float* __restrict__ tau_T,
    const int* __restrict__ image_ids, const int* __restrict__ text_ids,
    float* __restrict__ out) {
    int tid = threadIdx.x;
    int lane = tid & 63, wv = tid >> 6;
    float a[6] = {0, 0, 0, 0, 0, 0};
    for (int e = tid; e < 4096; e += 256) {
        a[0] += rows[0 * 4096 + e];
        a[1] += rows[1 * 4096 + e];
        a[2] += rows[2 * 4096 + e];
        a[3] += rows[3 * 4096 + e];
        a[4] += tau_I[image_ids[e]];
        a[5] += tau_T[text_ids[e]];
    }
    __shared__ float sred[4][6];
#pragma unroll
    for (int k = 0; k < 6; k++)
        for (int o = 32; o > 0; o >>= 1) a[k] += __shfl_xor(a[k], o);
    if (lane == 0)
#pragma unroll
        for (int k = 0; k < 6; k++) sred[wv][k] = a[k];
    __syncthreads();
    if (tid == 0) {
#pragma unroll
        for (int k = 0; k < 6; k++)
            a[k] = sred[0][k] + sred[1][k] + sred[2][k] + sred[3][k];
        const float inv = 1.0f / 4096.0f;
        out[0] = (a[0] + a[2]) * inv;
        out[1] = a[4] * inv;
        out[2] = a[5] * inv;
        out[3] = a[1] * inv;
        out[4] = a[3] * inv;
    }
}

extern "C" void kernel_launch(void* const* d_in, const int* in_sizes, int n_in,
                              void* d_out, int out_size, void* d_ws, size_t ws_size,
                              hipStream_t stream) {
    const float* img   = (const float*)d_in[0];
    const float* txt   = (const float*)d_in[1];
    const float* s_I   = (const float*)d_in[2];
    const float* s_T   = (const float*)d_in[3];
    const float* b_I   = (const float*)d_in[4];
    const float* b_T   = (const float*)d_in[5];
    const float* u_I   = (const float*)d_in[6];
    const float* u_T   = (const float*)d_in[7];
    const float* tau_I = (const float*)d_in[8];
    const float* tau_T = (const float*)d_in[9];
    const int* image_ids = (const int*)d_in[10];
    const int* text_ids  = (const int*)d_in[11];
    const int* epoch     = (const int*)d_in[12];
    float* out = (float*)d_out;
    const long long n = in_sizes[2];   // 1,000,000
    const int nfeat = in_sizes[0];     // 4096*512

    const size_t MB = 1024 * 1024;
    // ws layout (all within proven 144MB, actually < 24MB):
    //  [0,16MB): splits Ah/Al/Bh/Bl
    //  16MB: rowpart 4096x32x3 f32 (1.5MB) | 18MB: colpart (1.5MB)
    //  20MB: diag 16KB | 20.25MB: taur 16KB | 20.5MB: tauc 16KB
    //  21MB: rowbuf 4x4096 f32
    u16* Ah = (u16*)d_ws;
    u16* Al = Ah + (size_t)nfeat;
    u16* Bh = Al + (size_t)nfeat;
    u16* Bl = Bh + (size_t)nfeat;
    float* rowpart = (float*)((char*)d_ws + 16 * MB);
    float* colpart = (float*)((char*)d_ws + 18 * MB);
    float* diag    = (float*)((char*)d_ws + 20 * MB);
    float* taur    = (float*)((char*)d_ws + 20 * MB + 256 * 1024);
    float* tauc    = (float*)((char*)d_ws + 20 * MB + 512 * 1024);
    float* rows    = (float*)((char*)d_ws + 21 * MB);

    presplit<<<dim3((nfeat / 8 + 255) / 256, 2), 256, 0, stream>>>(
        img, txt, Ah, Al, Bh, Bl, nfeat,
        tau_I, tau_T, image_ids, text_ids, taur, tauc);

    gemm_flash<<<1024 + COPY_BLOCKS, 256, 0, stream>>>(
        Ah, Al, Bh, Bl, taur, tauc, rowpart, colpart, diag,
        s_I, s_T, b_I, b_T, u_I, u_T, tau_I, tau_T, out, n);

    FinArgs fa;
    fa.rowpart = rowpart; fa.colpart = colpart; fa.diag = diag;
    fa.tauI = tau_I; fa.sI = s_I; fa.bI = b_I; fa.uI = u_I;
    fa.tauT = tau_T; fa.sT = s_T; fa.bT = b_T; fa.uT = u_T;
    fa.img_ids = image_ids; fa.txt_ids = text_ids; fa.epoch_p = epoch;
    fa.out = out; fa.rowbuf = rows; fa.n = n;
    rows_final<<<32, 256, 0, stream>>>(fa);

    scalars<<<1, 256, 0, stream>>>(rows, tau_I, tau_T, image_ids, text_ids, out);
}

// Round 10
// 203.262 us; speedup vs baseline: 1.2712x; 1.0347x over previous
//
#include <hip/hip_runtime.h>

typedef unsigned short u16;
typedef unsigned int u32;

typedef __bf16 bf16x8 __attribute__((ext_vector_type(8)));
typedef float floatx4 __attribute__((ext_vector_type(4)));

__device__ __forceinline__ u16 f2bf(float f) {
    union { float f; u32 u; } c; c.f = f;
    u32 u = c.u;
    u32 r = u + 0x7FFFu + ((u >> 16) & 1u);   // round-to-nearest-even
    return (u16)(r >> 16);
}
__device__ __forceinline__ float bf2f(u16 x) {
    union { u32 u; float f; } c; c.u = ((u32)x) << 16; return c.f;
}

// online-softmax partial combine: (M,P0,P1) += (m,p0,p1)
// P0 = sum exp(y-M), P1 = sum y*exp(y-M)
__device__ __forceinline__ void comb(float& M, float& P0, float& P1,
                                     float m, float p0, float p1) {
    float nm = fmaxf(M, m);
    float s = __expf(M - nm), t = __expf(m - nm);
    P0 = P0 * s + p0 * t;
    P1 = P1 * s + p1 * t;
    M = nm;
}

// async global->LDS DMA, 16B per lane; lds base must be wave-uniform
__device__ __forceinline__ void dma16(const u16* g, u16* l) {
#if __has_builtin(__builtin_amdgcn_global_load_lds)
    __builtin_amdgcn_global_load_lds(
        (const __attribute__((address_space(1))) u32*)g,
        (__attribute__((address_space(3))) u32*)l, 16, 0, 0);
#else
    int lane = threadIdx.x & 63;
    *(uint4*)(l + lane * 8) = *(const uint4*)(g);
#endif
}

// ---------------------------------------------------------------------------
// presplit: f32 features -> bf16 hi/lo arrays; first 16 x-blocks also gather
// taur[i] = tau_I[image_ids[i]], tauc[j] = tau_T[text_ids[j]].
// ---------------------------------------------------------------------------
__global__ __launch_bounds__(256) void presplit(
    const float* __restrict__ a, const float* __restrict__ b,
    u16* __restrict__ Ah, u16* __restrict__ Al,
    u16* __restrict__ Bh, u16* __restrict__ Bl, int n,
    const float* __restrict__ tauI, const float* __restrict__ tauT,
    const int* __restrict__ img_ids, const int* __restrict__ txt_ids,
    float* __restrict__ taur, float* __restrict__ tauc) {
    if (blockIdx.y == 0 && blockIdx.x < 16) {
        int t = blockIdx.x * 256 + threadIdx.x;   // 0..4095
        taur[t] = tauI[img_ids[t]];
        tauc[t] = tauT[txt_ids[t]];
    }
    const float* src = blockIdx.y ? b : a;
    u16* dh = blockIdx.y ? Bh : Ah;
    u16* dl = blockIdx.y ? Bl : Al;
    int i = (blockIdx.x * 256 + threadIdx.x) * 8;
    if (i >= n) return;
    float4 v0 = *(const float4*)&src[i];
    float4 v1 = *(const float4*)&src[i + 4];
    float xs[8] = {v0.x, v0.y, v0.z, v0.w, v1.x, v1.y, v1.z, v1.w};
    u16 h[8], l[8];
#pragma unroll
    for (int e = 0; e < 8; e++) {
        h[e] = f2bf(xs[e]);
        l[e] = f2bf(xs[e] - bf2f(h[e]));
    }
    *(uint4*)&dh[i] = *(uint4*)h;
    *(uint4*)&dl[i] = *(uint4*)l;
}

// ---------------------------------------------------------------------------
// FUSED flash-GEMM + state copy.
// Blocks [0,1024): 128x128 sim tile via split bf16 MFMA; epilogue reduces the
//   tile to per-row/per-col softmax partials (M,P0,P1) of y=sim/tau.
//   Max-first: cheap shfl-max reduce, then ONE exp per element per side.
//   redbuf ALIASES the staging LDS (dead after K-loop) -> LDS stays 32KB.
// Blocks [1024,3072): copy the 8 f32 state arrays (256 blocks each, no div).
// ---------------------------------------------------------------------------
#define COPY_BLOCKS 2048

__global__ __launch_bounds__(256) void gemm_flash(
    const u16* __restrict__ Ah, const u16* __restrict__ Al,
    const u16* __restrict__ Bh, const u16* __restrict__ Bl,
    const float* __restrict__ taur, const float* __restrict__ tauc,
    float* __restrict__ rowpart, float* __restrict__ colpart,
    float* __restrict__ diag,
    const float* __restrict__ p0, const float* __restrict__ p1,
    const float* __restrict__ p2, const float* __restrict__ p3,
    const float* __restrict__ p4, const float* __restrict__ p5,
    const float* __restrict__ p6, const float* __restrict__ p7,
    float* __restrict__ out, long long n) {
    __shared__ __align__(16) u16 smem[4 * 128 * 32];   // 32768 B
    u16* sAh = smem;
    u16* sAl = smem + 4096;
    u16* sBh = smem + 8192;
    u16* sBl = smem + 12288;
    float* redbuf = (float*)smem;   // 1536 f32, reused AFTER the K-loop

    const int bid = blockIdx.x;
    if (bid >= 1024) {
        // ------------------ copy part: array k, block b ------------------
        const int cb = bid - 1024;
        const int k = cb >> 8, blk = cb & 255;
        const float* srcs[8] = {p0, p1, p2, p3, p4, p5, p6, p7};
        const float* src = srcs[k];
        float* dst = out + 5 + (size_t)k * (size_t)n;
        const long long G = (n - 3) >> 2;   // dest-aligned float4 groups
        for (long long g = (long long)blk * 256 + threadIdx.x; g < G;
             g += 256 * 256) {
            long long e = 3 + 4 * g;
            float4 q = {src[e], src[e + 1], src[e + 2], src[e + 3]};
            *(float4*)&dst[e] = q;          // (5+kn)+e ≡ 0 mod 4 -> 16B aligned
        }
        if (blk == 0) {
            int t = threadIdx.x;
            long long tail0 = 3 + 4 * G;
            int tcount = (int)(n - tail0);  // 0..3
            if (t < 3) dst[t] = src[t];
            else if (t < 3 + tcount) dst[tail0 + (t - 3)] = src[tail0 + (t - 3)];
        }
        return;
    }

    // ------------------ GEMM part ------------------
    const int tid  = threadIdx.x;
    const int wave = tid >> 6, lane = tid & 63;
    const int lr = lane & 15, quad = lane >> 4;
    const int waveM = wave >> 1, waveN = wave & 1;
    const int rowtile = bid >> 5, coltile = bid & 31;
    const int rowBase = rowtile * 128;
    const int colBase = coltile * 128;

    const int o0 = wave * 1024 + lane * 16;
    const int o1 = o0 + 4096;
    const int r0s = o0 >> 6, c0s = (o0 & 63) >> 1;
    const int r1s = o1 >> 6, c1s = (o1 & 63) >> 1;
    const int l0 = wave * 512;
    const int l1 = wave * 512 + 2048;

    floatx4 acc[4][4];
#pragma unroll
    for (int mi = 0; mi < 4; mi++)
#pragma unroll
        for (int ni = 0; ni < 4; ni++) acc[mi][ni] = (floatx4)0.0f;

    for (int k0 = 0; k0 < 512; k0 += 32) {
        __syncthreads();
        dma16(&Ah[(size_t)(rowBase + r0s) * 512 + k0 + c0s], sAh + l0);
        dma16(&Ah[(size_t)(rowBase + r1s) * 512 + k0 + c1s], sAh + l1);
        dma16(&Al[(size_t)(rowBase + r0s) * 512 + k0 + c0s], sAl + l0);
        dma16(&Al[(size_t)(rowBase + r1s) * 512 + k0 + c1s], sAl + l1);
        dma16(&Bh[(size_t)(colBase + r0s) * 512 + k0 + c0s], sBh + l0);
        dma16(&Bh[(size_t)(colBase + r1s) * 512 + k0 + c1s], sBh + l1);
        dma16(&Bl[(size_t)(colBase + r0s) * 512 + k0 + c0s], sBl + l0);
        dma16(&Bl[(size_t)(colBase + r1s) * 512 + k0 + c1s], sBl + l1);
        __syncthreads();

        bf16x8 afh[4], afl[4], bfh[4], bfl[4];
#pragma unroll
        for (int mi = 0; mi < 4; mi++) {
            int off = (waveM * 64 + mi * 16 + lr) * 32 + quad * 8;
            afh[mi] = *(const bf16x8*)&sAh[off];
            afl[mi] = *(const bf16x8*)&sAl[off];
        }
#pragma unroll
        for (int ni = 0; ni < 4; ni++) {
            int off = (waveN * 64 + ni * 16 + lr) * 32 + quad * 8;
            bfh[ni] = *(const bf16x8*)&sBh[off];
            bfl[ni] = *(const bf16x8*)&sBl[off];
        }
#pragma unroll
        for (int mi = 0; mi < 4; mi++)
#pragma unroll
            for (int ni = 0; ni < 4; ni++) {
                acc[mi][ni] = __builtin_amdgcn_mfma_f32_16x16x32_bf16(afh[mi], bfh[ni], acc[mi][ni], 0, 0, 0);
                acc[mi][ni] = __builtin_amdgcn_mfma_f32_16x16x32_bf16(afh[mi], bfl[ni], acc[mi][ni], 0, 0, 0);
                acc[mi][ni] = __builtin_amdgcn_mfma_f32_16x16x32_bf16(afl[mi], bfh[ni], acc[mi][ni], 0, 0, 0);
            }
    }
    __syncthreads();   // staging LDS dead beyond here; redbuf may alias it

    // --- epilogue ---
    // C/D layout: v(rr,cc): rr = rowBase+waveM*64+mi*16+quad*4+r,
    //                       cc = colBase+waveN*64+ni*16+lr   [m89/m91]

    // diagonal capture (raw sim value)
    if (rowtile == coltile && waveM == waveN) {
#pragma unroll
        for (int mi = 0; mi < 4; mi++)
#pragma unroll
            for (int r = 0; r < 4; r++)
                if (lr == quad * 4 + r)
                    diag[colBase + waveN * 64 + mi * 16 + lr] = acc[mi][mi][r];
    }

    // row partials: max-first, then one exp per element
#pragma unroll
    for (int mi = 0; mi < 4; mi++) {
#pragma unroll
        for (int r = 0; r < 4; r++) {
            int row_local = waveM * 64 + mi * 16 + quad * 4 + r;
            float vmax = fmaxf(fmaxf(acc[mi][0][r], acc[mi][1][r]),
                               fmaxf(acc[mi][2][r], acc[mi][3][r]));
#pragma unroll
            for (int mask = 1; mask <= 8; mask <<= 1)
                vmax = fmaxf(vmax, __shfl_xor(vmax, mask));
            float it = 1.0f / taur[rowBase + row_local];
            float M = vmax * it;
            float P0 = 0.f, P1 = 0.f;
#pragma unroll
            for (int ni = 0; ni < 4; ni++) {
                float y = acc[mi][ni][r] * it;
                float e = __expf(y - M);
                P0 += e;
                P1 += y * e;
            }
#pragma unroll
            for (int mask = 1; mask <= 8; mask <<= 1) {
                P0 += __shfl_xor(P0, mask);
                P1 += __shfl_xor(P1, mask);
            }
            if (lr == 0) {
                int x = (row_local * 2 + waveN) * 3;
                redbuf[x] = M; redbuf[x + 1] = P0; redbuf[x + 2] = P1;
            }
        }
    }

    // col partials: max-first, then one exp per element
#pragma unroll
    for (int ni = 0; ni < 4; ni++) {
        int col_local = waveN * 64 + ni * 16 + lr;
        float vmax = -3.4e38f;
#pragma unroll
        for (int mi = 0; mi < 4; mi++)
            vmax = fmaxf(vmax,
                fmaxf(fmaxf(acc[mi][ni][0], acc[mi][ni][1]),
                      fmaxf(acc[mi][ni][2], acc[mi][ni][3])));
#pragma unroll
        for (int mask = 16; mask <= 32; mask <<= 1)
            vmax = fmaxf(vmax, __shfl_xor(vmax, mask));
        float it = 1.0f / tauc[colBase + col_local];
        float M = vmax * it;
        float P0 = 0.f, P1 = 0.f;
#pragma unroll
        for (int mi = 0; mi < 4; mi++)
#pragma unroll
            for (int r = 0; r < 4; r++) {
                float y = acc[mi][ni][r] * it;
                float e = __expf(y - M);
                P0 += e;
                P1 += y * e;
            }
#pragma unroll
        for (int mask = 16; mask <= 32; mask <<= 1) {
            P0 += __shfl_xor(P0, mask);
            P1 += __shfl_xor(P1, mask);
        }
        if (quad == 0) {
            int x = 768 + (col_local * 2 + waveM) * 3;
            redbuf[x] = M; redbuf[x + 1] = P0; redbuf[x + 2] = P1;
        }
    }
    __syncthreads();

    if (tid < 128) {
        int x = tid * 6;
        float M = redbuf[x], P0 = redbuf[x + 1], P1 = redbuf[x + 2];
        comb(M, P0, P1, redbuf[x + 3], redbuf[x + 4], redbuf[x + 5]);
        float* dst = &rowpart[(size_t)(rowBase + tid) * 96 + coltile * 3];
        dst[0] = M; dst[1] = P0; dst[2] = P1;
    } else {
        int c = tid - 128;
        int x = 768 + c * 6;
        float M = redbuf[x], P0 = redbuf[x + 1], P1 = redbuf[x + 2];
        comb(M, P0, P1, redbuf[x + 3], redbuf[x + 4], redbuf[x + 5]);
        float* dst = &colpart[(size_t)(colBase + c) * 96 + rowtile * 3];
        dst[0] = M; dst[1] = P0; dst[2] = P1;
    }
}

// ---------------------------------------------------------------------------
// Final per-row/col state update from partials. One thread per (side,row).
// S0 = P0*e - exp(-b), S1 = (P1 - y_ii*P0)*e, e = exp(M - y_ii - b),
// b = max(M - y_ii, old_b), y_ii = diag/tau.
// ---------------------------------------------------------------------------
struct FinArgs {
    const float* rowpart; const float* colpart; const float* diag;
    const float* tauI; const float* sI; const float* bI; const float* uI;
    const float* tauT; const float* sT; const float* bT; const float* uT;
    const int* img_ids; const int* txt_ids; const int* epoch_p;
    float* out; float* rowbuf; long long n;
};

__global__ __launch_bounds__(256) void rows_final(FinArgs a) {
    int t = blockIdx.x * 256 + threadIdx.x;   // 8192 threads
    int side = t >> 12, i = t & 4095;
    const float* part   = side ? a.colpart : a.rowpart;
    const int*   ids    = side ? a.txt_ids : a.img_ids;
    const float* tau_in = side ? a.tauT : a.tauI;
    const float* s_in   = side ? a.sT   : a.sI;
    const float* b_in   = side ? a.bT   : a.bI;
    const float* u_in   = side ? a.uT   : a.uI;

    const float* p = part + (size_t)i * 96;
    float M = -3.4e38f, P0 = 0.f, P1 = 0.f;
#pragma unroll 4
    for (int k = 0; k < 32; k++)
        comb(M, P0, P1, p[3 * k], p[3 * k + 1], p[3 * k + 2]);

    const int id = ids[i];
    const float tau   = tau_in[id];
    const float old_b = b_in[id];
    const float old_s = s_in[id];
    const float old_u = u_in[id];
    const float y_ii  = a.diag[i] / tau;

    float b_row = fmaxf(M - y_ii, old_b);
    float e  = expf(M - y_ii - b_row);
    float S0 = P0 * e - expf(-b_row);           // mask diagonal term
    float S1 = (P1 - y_ii * P0) * e;            // diagonal contributes 0

    float g = S0;
    float sI = (*a.epoch_p == 0) ? g
             : 0.2f * old_s * expf(old_b - b_row) + 0.8f * g;
    float denom = sI + 1e-10f;
    float wsum = S1 / denom;
    float lossr = tau * wsum;
    float tw = logf(sI * (1.0f / 4095.0f)) + b_row + 8.0f - wsum;
    tw = fminf(fmaxf(tw, -5.0f), 5.0f);
    float uval = 0.5f * old_u + 0.5f * tw;
    float taun = fminf(fmaxf(tau - 1e-5f * uval, 0.005f), 0.05f);

    float* sect = a.out + 5;
    sect[(size_t)(0 + side) * (size_t)a.n + id] = sI;
    sect[(size_t)(2 + side) * (size_t)a.n + id] = b_row;
    sect[(size_t)(4 + side) * (size_t)a.n + id] = uval;
    sect[(size_t)(6 + side) * (size_t)a.n + id] = taun;

    a.rowbuf[(2 * side + 0) * 4096 + i] = lossr;
    a.rowbuf[(2 * side + 1) * 4096 + i] = tw;
}

// ---------------------------------------------------------------------------
// Final 5 scalars (proven round 6).
// ---------------------------------------------------------------------------
__global__ __launch_bounds__(256) void scalars(
    const float* __restrict__ rows,
    const float* __restrict__ tau_I, const float* __restrict__ tau_T,
    const int* __restrict__ image_ids, const int* __restrict__ text_ids,
    float* __restrict__ out) {
    int tid = threadIdx.x;
    int lane = tid & 63, wv = tid >> 6;
    float a[6] = {0, 0, 0, 0, 0, 0};
    for (int e = tid; e < 4096; e += 256) {
        a[0] += rows[0 * 4096 + e];
        a[1] += rows[1 * 4096 + e];
        a[2] += rows[2 * 4096 + e];
        a[3] += rows[3 * 4096 + e];
        a[4] += tau_I[image_ids[e]];
        a[5] += tau_T[text_ids[e]];
    }
    __shared__ float sred[4][6];
#pragma unroll
    for (int k = 0; k < 6; k++)
        for (int o = 32; o > 0; o >>= 1) a[k] += __shfl_xor(a[k], o);
    if (lane == 0)
#pragma unroll
        for (int k = 0; k < 6; k++) sred[wv][k] = a[k];
    __syncthreads();
    if (tid == 0) {
#pragma unroll
        for (int k = 0; k < 6; k++)
            a[k] = sred[0][k] + sred[1][k] + sred[2][k] + sred[3][k];
        const float inv = 1.0f / 4096.0f;
        out[0] = (a[0] + a[2]) * inv;
        out[1] = a[4] * inv;
        out[2] = a[5] * inv;
        out[3] = a[1] * inv;
        out[4] = a[3] * inv;
    }
}

extern "C" void kernel_launch(void* const* d_in, const int* in_sizes, int n_in,
                              void* d_out, int out_size, void* d_ws, size_t ws_size,
                              hipStream_t stream) {
    const float* img   = (const float*)d_in[0];
    const float* txt   = (const float*)d_in[1];
    const float* s_I   = (const float*)d_in[2];
    const float* s_T   = (const float*)d_in[3];
    const float* b_I   = (const float*)d_in[4];
    const float* b_T   = (const float*)d_in[5];
    const float* u_I   = (const float*)d_in[6];
    const float* u_T   = (const float*)d_in[7];
    const float* tau_I = (const float*)d_in[8];
    const float* tau_T = (const float*)d_in[9];
    const int* image_ids = (const int*)d_in[10];
    const int* text_ids  = (const int*)d_in[11];
    const int* epoch     = (const int*)d_in[12];
    float* out = (float*)d_out;
    const long long n = in_sizes[2];   // 1,000,000
    const int nfeat = in_sizes[0];     // 4096*512

    const size_t MB = 1024 * 1024;
    // ws layout (< 24MB):
    //  [0,16MB): splits Ah/Al/Bh/Bl
    //  16MB: rowpart 4096x32x3 f32 | 18MB: colpart | 20MB: diag
    //  20.25MB: taur | 20.5MB: tauc | 21MB: rowbuf 4x4096 f32
    u16* Ah = (u16*)d_ws;
    u16* Al = Ah + (size_t)nfeat;
    u16* Bh = Al + (size_t)nfeat;
    u16* Bl = Bh + (size_t)nfeat;
    float* rowpart = (float*)((char*)d_ws + 16 * MB);
    float* colpart = (float*)((char*)d_ws + 18 * MB);
    float* diag    = (float*)((char*)d_ws + 20 * MB);
    float* taur    = (float*)((char*)d_ws + 20 * MB + 256 * 1024);
    float* tauc    = (float*)((char*)d_ws + 20 * MB + 512 * 1024);
    float* rows    = (float*)((char*)d_ws + 21 * MB);

    presplit<<<dim3((nfeat / 8 + 255) / 256, 2), 256, 0, stream>>>(
        img, txt, Ah, Al, Bh, Bl, nfeat,
        tau_I, tau_T, image_ids, text_ids, taur, tauc);

    gemm_flash<<<1024 + COPY_BLOCKS, 256, 0, stream>>>(
        Ah, Al, Bh, Bl, taur, tauc, rowpart, colpart, diag,
        s_I, s_T, b_I, b_T, u_I, u_T, tau_I, tau_T, out, n);

    FinArgs fa;
    fa.rowpart = rowpart; fa.colpart = colpart; fa.diag = diag;
    fa.tauI = tau_I; fa.sI = s_I; fa.bI = b_I; fa.uI = u_I;
    fa.tauT = tau_T; fa.sT = s_T; fa.bT = b_T; fa.uT = u_T;
    fa.img_ids = image_ids; fa.txt_ids = text_ids; fa.epoch_p = epoch;
    fa.out = out; fa.rowbuf = rows; fa.n = n;
    rows_final<<<32, 256, 0, stream>>>(fa);

    scalars<<<1, 256, 0, stream>>>(rows, tau_I, tau_T, image_ids, text_ids, out);
}